// Round 2
// baseline (1111.059 us; speedup 1.0000x reference)
//
#include <hip/hip_runtime.h>
#include <math.h>

#define B_TOTAL 16384
#define T_STEPS 20

// ---------------------------------------------------------------------------
// Overflow-safe activations (graceful at +-inf exp)
__device__ __forceinline__ float sigf(float x) {
    return 1.0f / (1.0f + __expf(-x));
}
__device__ __forceinline__ float tanhf_fast(float x) {
    float e = __expf(2.0f * x);
    return 1.0f - 2.0f / (e + 1.0f);   // large x: e=inf -> 1; large -x: e=0 -> -1
}

// NOTE: was a macro; macro params named z/w collided with .z/.w member names.
__device__ __forceinline__ void fma4(float4& acc, const float4& wv, float s) {
    acc.x = fmaf(wv.x, s, acc.x);
    acc.y = fmaf(wv.y, s, acc.y);
    acc.z = fmaf(wv.z, s, acc.z);
    acc.w = fmaf(wv.w, s, acc.w);
}

// ---------------------------------------------------------------------------
// Fused 5-layer LSTM. lane j = hidden unit, each thread handles 2 batch elems.
// LDS: hseq[NE][640] (inter-layer h sequences, overwritten in place per layer)
//      W4ih[32][32] float4, W4hh[32][32] float4 (gate-interleaved, k-major)
//      bias4[32] float4
// BLOCK=256 -> NE=16 elems, 74,240 B LDS (needs >64KB dynamic-LDS attribute)
// BLOCK=128 -> NE=8  elems, 53,760 B LDS (fallback, always launchable)
template <int BLOCK>
__global__ __launch_bounds__(BLOCK, 2)
void lstm5_kernel(const float* __restrict__ accel, const float* __restrict__ gyro,
                  const float* __restrict__ aWih0, const float* __restrict__ aWihR,
                  const float* __restrict__ aWhh,  const float* __restrict__ aBih,
                  const float* __restrict__ aBhh,
                  const float* __restrict__ gWih0, const float* __restrict__ gWihR,
                  const float* __restrict__ gWhh,  const float* __restrict__ gBih,
                  const float* __restrict__ gBhh,
                  float* __restrict__ hseq_out /* [2][B][640] */) {
    constexpr int EH = BLOCK / 32;   // e-groups
    constexpr int NE = 2 * EH;       // batch elems per block
    const int tid = threadIdx.x;
    const int j   = tid & 31;        // hidden unit
    const int eh  = tid >> 5;        // 0..EH-1
    const int sensor = blockIdx.y;
    const int bbase  = blockIdx.x * NE;

    const float* xin  = sensor ? gyro  : accel;
    const float* Wih0 = sensor ? gWih0 : aWih0;
    const float* WihR = sensor ? gWihR : aWihR;
    const float* Whh  = sensor ? gWhh  : aWhh;
    const float* Bih  = sensor ? gBih  : aBih;
    const float* Bhh  = sensor ? gBhh  : aBhh;

    extern __shared__ char smem[];
    float*  hseq  = (float*)smem;                      // NE*640 floats
    float4* W4ih  = (float4*)(smem + NE * 640 * 4);    // [32][32]
    float4* W4hh  = W4ih + 32 * 32;                    // [32][32]
    float4* bias4 = W4hh + 32 * 32;                    // [32]

    const int eA = eh, eB = eh + EH;
    const int bA = bbase + eA, bB = bbase + eB;

    for (int l = 0; l < 5; ++l) {
        __syncthreads();   // everyone done with previous layer's weights
        // ---- stage layer-l weights, gate-interleaved ----
        {
            const float* Wi = (l == 0) ? Wih0 : (WihR + (l - 1) * 4096);
            const int K = (l == 0) ? 3 : 32;
            for (int idx = tid; idx < K * 32; idx += BLOCK) {
                int k = idx >> 5, jj = idx & 31;
                W4ih[idx] = make_float4(Wi[jj * K + k],        Wi[(jj + 32) * K + k],
                                        Wi[(jj + 64) * K + k], Wi[(jj + 96) * K + k]);
            }
            const float* Wh = Whh + l * 4096;
            for (int idx = tid; idx < 32 * 32; idx += BLOCK) {
                int k = idx >> 5, jj = idx & 31;
                W4hh[idx] = make_float4(Wh[jj * 32 + k],        Wh[(jj + 32) * 32 + k],
                                        Wh[(jj + 64) * 32 + k], Wh[(jj + 96) * 32 + k]);
            }
            for (int idx = tid; idx < 32; idx += BLOCK) {
                bias4[idx] = make_float4(
                    Bih[l * 128 + idx]      + Bhh[l * 128 + idx],
                    Bih[l * 128 + idx + 32] + Bhh[l * 128 + idx + 32],
                    Bih[l * 128 + idx + 64] + Bhh[l * 128 + idx + 64],
                    Bih[l * 128 + idx + 96] + Bhh[l * 128 + idx + 96]);
            }
        }
        __syncthreads();

        float cA = 0.f, cB = 0.f;
        for (int t = 0; t < T_STEPS; ++t) {
            float4 zA = bias4[j];
            float4 zB = zA;
            // ---- input projection ----
            if (l == 0) {
                const float* xa = xin + (bA * T_STEPS + t) * 3;
                const float* xb = xin + (bB * T_STEPS + t) * 3;
#pragma unroll
                for (int k = 0; k < 3; ++k) {
                    float4 wv = W4ih[k * 32 + j];
                    float sa = xa[k], sb = xb[k];
                    fma4(zA, wv, sa);
                    fma4(zB, wv, sb);
                }
            } else {
                const float4* xa4 = (const float4*)(hseq + eA * 640 + t * 32);
                const float4* xb4 = (const float4*)(hseq + eB * 640 + t * 32);
#pragma unroll
                for (int kc = 0; kc < 8; ++kc) {
                    float4 xa = xa4[kc], xb = xb4[kc];
                    float4 w0 = W4ih[(kc * 4 + 0) * 32 + j]; fma4(zA, w0, xa.x); fma4(zB, w0, xb.x);
                    float4 w1 = W4ih[(kc * 4 + 1) * 32 + j]; fma4(zA, w1, xa.y); fma4(zB, w1, xb.y);
                    float4 w2 = W4ih[(kc * 4 + 2) * 32 + j]; fma4(zA, w2, xa.z); fma4(zB, w2, xb.z);
                    float4 w3 = W4ih[(kc * 4 + 3) * 32 + j]; fma4(zA, w3, xa.w); fma4(zB, w3, xb.w);
                }
            }
            // ---- recurrent projection (h at t-1 lives at hseq[t-1]) ----
            if (t > 0) {
                const float4* ha4 = (const float4*)(hseq + eA * 640 + (t - 1) * 32);
                const float4* hb4 = (const float4*)(hseq + eB * 640 + (t - 1) * 32);
#pragma unroll
                for (int kc = 0; kc < 8; ++kc) {
                    float4 xa = ha4[kc], xb = hb4[kc];
                    float4 w0 = W4hh[(kc * 4 + 0) * 32 + j]; fma4(zA, w0, xa.x); fma4(zB, w0, xb.x);
                    float4 w1 = W4hh[(kc * 4 + 1) * 32 + j]; fma4(zA, w1, xa.y); fma4(zB, w1, xb.y);
                    float4 w2 = W4hh[(kc * 4 + 2) * 32 + j]; fma4(zA, w2, xa.z); fma4(zB, w2, xb.z);
                    float4 w3 = W4hh[(kc * 4 + 3) * 32 + j]; fma4(zA, w3, xa.w); fma4(zB, w3, xb.w);
                }
            }
            // ---- gates / state update / write h (in-place over input slot) ----
            {
                float i_ = sigf(zA.x), f_ = sigf(zA.y), g_ = tanhf_fast(zA.z), o_ = sigf(zA.w);
                cA = f_ * cA + i_ * g_;
                hseq[eA * 640 + t * 32 + j] = o_ * tanhf_fast(cA);
            }
            {
                float i_ = sigf(zB.x), f_ = sigf(zB.y), g_ = tanhf_fast(zB.z), o_ = sigf(zB.w);
                cB = f_ * cB + i_ * g_;
                hseq[eB * 640 + t * 32 + j] = o_ * tanhf_fast(cB);
            }
        }
    }
    __syncthreads();
    // ---- copy final-layer sequences to workspace (block range is contiguous) ----
    float* dst = hseq_out + (size_t)sensor * B_TOTAL * 640 + (size_t)bbase * 640;
    const float4* s4 = (const float4*)hseq;
    float4* d4 = (float4*)dst;
    for (int i = tid; i < NE * 160; i += BLOCK) d4[i] = s4[i];
}

// ---------------------------------------------------------------------------
// fc1_w [128][1280] -> W1T [1280][128] so fc reads are lane-coalesced
__global__ void transpose_w1(const float* __restrict__ w1, float* __restrict__ w1t) {
    int idx = blockIdx.x * blockDim.x + threadIdx.x;   // 1280*128
    int kk = idx >> 7, m = idx & 127;
    w1t[idx] = w1[m * 1280 + kk];
}

// ---------------------------------------------------------------------------
// Fused fc1 + ReLU + fc2. 256 thr = 32 m-quads x 8 b-quads; thread owns 4m x 4b.
// W1T streamed from L2 (655 KB, resident); X as broadcast float4; no LDS.
__global__ __launch_bounds__(256, 2)
void fc_kernel(const float* __restrict__ hseqbuf, const float* __restrict__ w1t,
               const float* __restrict__ fc1_b, const float* __restrict__ fc2_w,
               const float* __restrict__ fc2_b, float* __restrict__ out) {
    const int tid = threadIdx.x;
    const int mq = tid & 31;          // m = 4*mq + mc
    const int bq = tid >> 5;          // 0..7
    const int b0 = blockIdx.x * 32 + bq * 4;

    float acc[4][4];
#pragma unroll
    for (int bi = 0; bi < 4; ++bi)
#pragma unroll
        for (int mc = 0; mc < 4; ++mc) acc[bi][mc] = 0.f;

    const float4* W1T4 = (const float4*)w1t;
    for (int half = 0; half < 2; ++half) {
        const float4* X4 = (const float4*)(hseqbuf + (size_t)half * B_TOTAL * 640);
        for (int c = 0; c < 80; ++c) {           // 8-kk chunks over 640
            float xs[4][8];
#pragma unroll
            for (int bi = 0; bi < 4; ++bi) {
                float4 u0 = X4[(b0 + bi) * 160 + c * 2];
                float4 u1 = X4[(b0 + bi) * 160 + c * 2 + 1];
                xs[bi][0] = u0.x; xs[bi][1] = u0.y; xs[bi][2] = u0.z; xs[bi][3] = u0.w;
                xs[bi][4] = u1.x; xs[bi][5] = u1.y; xs[bi][6] = u1.z; xs[bi][7] = u1.w;
            }
#pragma unroll
            for (int k = 0; k < 8; ++k) {
                float4 wv = W1T4[(half * 640 + c * 8 + k) * 32 + mq];
#pragma unroll
                for (int bi = 0; bi < 4; ++bi) {
                    float xv = xs[bi][k];
                    acc[bi][0] = fmaf(wv.x, xv, acc[bi][0]);
                    acc[bi][1] = fmaf(wv.y, xv, acc[bi][1]);
                    acc[bi][2] = fmaf(wv.z, xv, acc[bi][2]);
                    acc[bi][3] = fmaf(wv.w, xv, acc[bi][3]);
                }
            }
        }
    }

    // epilogue: bias + ReLU + fc2 partial + lane-reduce over mq
    float4 b1 = ((const float4*)fc1_b)[mq];
    float4 w2v[5];
#pragma unroll
    for (int n = 0; n < 5; ++n) w2v[n] = ((const float4*)fc2_w)[n * 32 + mq];

#pragma unroll
    for (int bi = 0; bi < 4; ++bi) {
        float v0 = fmaxf(acc[bi][0] + b1.x, 0.f);
        float v1 = fmaxf(acc[bi][1] + b1.y, 0.f);
        float v2 = fmaxf(acc[bi][2] + b1.z, 0.f);
        float v3 = fmaxf(acc[bi][3] + b1.w, 0.f);
        float p[5];
#pragma unroll
        for (int n = 0; n < 5; ++n) {
            p[n] = fmaf(v0, w2v[n].x, fmaf(v1, w2v[n].y, fmaf(v2, w2v[n].z, v3 * w2v[n].w)));
#pragma unroll
            for (int s = 16; s > 0; s >>= 1) p[n] += __shfl_down(p[n], s, 32);
        }
        if (mq == 0) {
#pragma unroll
            for (int n = 0; n < 5; ++n) out[(b0 + bi) * 5 + n] = p[n] + fc2_b[n];
        }
    }
}

// ---------------------------------------------------------------------------
extern "C" void kernel_launch(void* const* d_in, const int* in_sizes, int n_in,
                              void* d_out, int out_size, void* d_ws, size_t ws_size,
                              hipStream_t stream) {
    const float* accel  = (const float*)d_in[0];
    const float* gyro   = (const float*)d_in[1];
    const float* aWih0  = (const float*)d_in[2];
    const float* aWihR  = (const float*)d_in[3];
    const float* aWhh   = (const float*)d_in[4];
    const float* aBih   = (const float*)d_in[5];
    const float* aBhh   = (const float*)d_in[6];
    const float* gWih0  = (const float*)d_in[7];
    const float* gWihR  = (const float*)d_in[8];
    const float* gWhh   = (const float*)d_in[9];
    const float* gBih   = (const float*)d_in[10];
    const float* gBhh   = (const float*)d_in[11];
    const float* fc1_w  = (const float*)d_in[12];
    const float* fc1_b  = (const float*)d_in[13];
    const float* fc2_w  = (const float*)d_in[14];
    const float* fc2_b  = (const float*)d_in[15];
    float* out = (float*)d_out;

    float* ws      = (float*)d_ws;
    float* hseqbuf = ws;                              // 2*B*640 floats (84 MB)
    float* w1t     = ws + (size_t)2 * B_TOTAL * 640;  // 1280*128 floats

    // weight transpose for fc
    hipLaunchKernelGGL(transpose_w1, dim3(640), dim3(256), 0, stream, fc1_w, w1t);

    // LSTM: prefer 256-thread/16-elem variant (74,240 B dynamic LDS)
    const int SMEM_BIG = 16 * 640 * 4 + 2 * 32 * 32 * 16 + 32 * 16;   // 74,240
    hipError_t attr_ok = hipFuncSetAttribute(
        reinterpret_cast<const void*>(&lstm5_kernel<256>),
        hipFuncAttributeMaxDynamicSharedMemorySize, SMEM_BIG);
    if (attr_ok == hipSuccess) {
        hipLaunchKernelGGL((lstm5_kernel<256>), dim3(B_TOTAL / 16, 2), dim3(256),
                           SMEM_BIG, stream,
                           accel, gyro, aWih0, aWihR, aWhh, aBih, aBhh,
                           gWih0, gWihR, gWhh, gBih, gBhh, hseqbuf);
    } else {
        const int SMEM_SMALL = 8 * 640 * 4 + 2 * 32 * 32 * 16 + 32 * 16; // 53,760
        hipLaunchKernelGGL((lstm5_kernel<128>), dim3(B_TOTAL / 8, 2), dim3(128),
                           SMEM_SMALL, stream,
                           accel, gyro, aWih0, aWihR, aWhh, aBih, aBhh,
                           gWih0, gWihR, gWhh, gBih, gBhh, hseqbuf);
    }

    // fused fc1+ReLU+fc2
    hipLaunchKernelGGL(fc_kernel, dim3(B_TOTAL / 32), dim3(256), 0, stream,
                       hseqbuf, w1t, fc1_b, fc2_w, fc2_b, out);
}

// Round 3
// 559.196 us; speedup vs baseline: 1.9869x; 1.9869x over previous
//
#include <hip/hip_runtime.h>
#include <math.h>

#define B_TOTAL 16384
#define T_STEPS 20

typedef __attribute__((ext_vector_type(8))) __bf16 bf16x8;
typedef __attribute__((ext_vector_type(4))) float f32x4;

// ---------------------------------------------------------------------------
// Overflow-safe activations (graceful at +-inf exp)
__device__ __forceinline__ float sigf(float x) {
    return 1.0f / (1.0f + __expf(-x));
}
__device__ __forceinline__ float tanhf_fast(float x) {
    float e = __expf(2.0f * x);
    return 1.0f - 2.0f / (e + 1.0f);   // large x: e=inf -> 1; large -x: e=0 -> -1
}

// ---------------------------------------------------------------------------
// Fused 5-layer LSTM via bf16 MFMA with hi/lo compensation.
//
// Orientation: D[gate-rows][elems].  Gate-rows reordered unit-major:
//   row = unit_local*4 + gate  (gate in PyTorch order i,f,g,o)
// so C-frag lane (col e = lane&15, quad) holds regs = the 4 gates of unit
// (tile*4 + quad) for elem e -> activations fully in-register.
//
// Wave w (of 4) owns gate-tiles {2w, 2w+1} = units 8w..8w+7.
// Weights stationary in VGPRs (A-frags, hi+lo). h-sequence in LDS as
// shi/slo[t][chunk=unit>>3][e][unit&7] bf16 -> B-frag reads are contiguous
// 1024 B per t (conflict-free ds_read_b128).
__global__ __launch_bounds__(256, 2)
void lstm5_mfma(const float* __restrict__ accel, const float* __restrict__ gyro,
                const float* __restrict__ aWih0, const float* __restrict__ aWihR,
                const float* __restrict__ aWhh,  const float* __restrict__ aBih,
                const float* __restrict__ aBhh,
                const float* __restrict__ gWih0, const float* __restrict__ gWihR,
                const float* __restrict__ gWhh,  const float* __restrict__ gBih,
                const float* __restrict__ gBhh,
                float* __restrict__ hseq_out /* [2][B][640] */) {
    const int tid  = threadIdx.x;
    const int w    = tid >> 6;        // wave 0..3
    const int lane = tid & 63;
    const int e    = lane & 15;       // elem (B-frag col / C col)
    const int quad = lane >> 4;       // 0..3
    const int sensor = blockIdx.y;
    const int bbase  = blockIdx.x * 16;

    const float* xin  = sensor ? gyro  : accel;
    const float* Wih0 = sensor ? gWih0 : aWih0;
    const float* WihR = sensor ? gWihR : aWihR;
    const float* Whh  = sensor ? gWhh  : aWhh;
    const float* Bih  = sensor ? gBih  : aBih;
    const float* Bhh  = sensor ? gBhh  : aBhh;

    __shared__ __align__(16) float  xs[960];          // [e][t][3]
    __shared__ __align__(16) __bf16 shi[20 * 512];    // [t][chunk][e][j]
    __shared__ __align__(16) __bf16 slo[20 * 512];

    // ---- stage layer-0 inputs (block's 16 elems are contiguous) ----
    {
        const float4* src = (const float4*)(xin + (size_t)bbase * 60);
        if (tid < 240) ((float4*)xs)[tid] = src[tid];
    }
    __syncthreads();

    // unit handled by (tile, quad):
    const int ug0 = (w * 2 + 0) * 4 + quad;   // tile 0 unit
    const int ug1 = (w * 2 + 1) * 4 + quad;   // tile 1 unit

    // A-frag loader: lane's row m = lane&15 -> (u_local=m>>2, gate=m&3);
    // orig W row = gate*32 + u_global; k-range = quad*8..+8.
    const int m_row   = lane & 15;
    const int ug_t0   = (w * 2 + 0) * 4 + (m_row >> 2);
    const int ug_t1   = (w * 2 + 1) * 4 + (m_row >> 2);
    const int orow_t0 = (m_row & 3) * 32 + ug_t0;
    const int orow_t1 = (m_row & 3) * 32 + ug_t1;

    bf16x8 wih_h0, wih_l0, wih_h1, wih_l1;
    bf16x8 whh_h0, whh_l0, whh_h1, whh_l1;
    float  bias0[4], bias1[4];
    float  c0 = 0.f, c1 = 0.f;

#define LOAD_FRAG(Wsrc, orow, fh, fl)                         \
    {                                                         \
        const float* p_ = (Wsrc) + (orow) * 32 + quad * 8;    \
        _Pragma("unroll")                                     \
        for (int jj = 0; jj < 8; ++jj) {                      \
            float v_  = p_[jj];                               \
            __bf16 h_ = (__bf16)v_;                           \
            (fh)[jj]  = h_;                                   \
            (fl)[jj]  = (__bf16)(v_ - (float)h_);             \
        }                                                     \
    }

#define LOAD_BIAS(l)                                                        \
    {                                                                       \
        _Pragma("unroll")                                                   \
        for (int r = 0; r < 4; ++r) {                                       \
            bias0[r] = Bih[(l) * 128 + r * 32 + ug0] + Bhh[(l) * 128 + r * 32 + ug0]; \
            bias1[r] = Bih[(l) * 128 + r * 32 + ug1] + Bhh[(l) * 128 + r * 32 + ug1]; \
        }                                                                   \
    }

    // activation + h write (c0/c1 updated; h split hi/lo into LDS)
#define ACT_STORE(t)                                                        \
    {                                                                       \
        float i0 = sigf(acc0[0]), f0 = sigf(acc0[1]);                       \
        float g0 = tanhf_fast(acc0[2]), o0 = sigf(acc0[3]);                 \
        c0 = f0 * c0 + i0 * g0;                                             \
        float h0 = o0 * tanhf_fast(c0);                                     \
        float i1 = sigf(acc1[0]), f1 = sigf(acc1[1]);                       \
        float g1 = tanhf_fast(acc1[2]), o1 = sigf(acc1[3]);                 \
        c1 = f1 * c1 + i1 * g1;                                             \
        float h1 = o1 * tanhf_fast(c1);                                     \
        __syncthreads();  /* all waves done reading shi/slo[t] */           \
        int i0x = (t) * 512 + w * 128 + e * 8 + quad;                       \
        int i1x = i0x + 4;                                                  \
        __bf16 hh0 = (__bf16)h0;                                            \
        shi[i0x] = hh0; slo[i0x] = (__bf16)(h0 - (float)hh0);               \
        __bf16 hh1 = (__bf16)h1;                                            \
        shi[i1x] = hh1; slo[i1x] = (__bf16)(h1 - (float)hh1);               \
        __syncthreads();  /* writes visible before next step's reads */     \
    }

    // ================= layer 0 (ih is K=3, done in VALU) =================
    {
        LOAD_FRAG(Whh, orow_t0, whh_h0, whh_l0);
        LOAD_FRAG(Whh, orow_t1, whh_h1, whh_l1);
        LOAD_BIAS(0);
        float w0reg[2][4][3];
#pragma unroll
        for (int r = 0; r < 4; ++r)
#pragma unroll
            for (int k = 0; k < 3; ++k) {
                w0reg[0][r][k] = Wih0[(r * 32 + ug0) * 3 + k];
                w0reg[1][r][k] = Wih0[(r * 32 + ug1) * 3 + k];
            }
        c0 = 0.f; c1 = 0.f;

        for (int t = 0; t < T_STEPS; ++t) {
            f32x4 acc0 = {bias0[0], bias0[1], bias0[2], bias0[3]};
            f32x4 acc1 = {bias1[0], bias1[1], bias1[2], bias1[3]};
            float x0 = xs[e * 60 + t * 3 + 0];
            float x1 = xs[e * 60 + t * 3 + 1];
            float x2 = xs[e * 60 + t * 3 + 2];
#pragma unroll
            for (int r = 0; r < 4; ++r) {
                acc0[r] = fmaf(w0reg[0][r][0], x0,
                          fmaf(w0reg[0][r][1], x1,
                          fmaf(w0reg[0][r][2], x2, acc0[r])));
                acc1[r] = fmaf(w0reg[1][r][0], x0,
                          fmaf(w0reg[1][r][1], x1,
                          fmaf(w0reg[1][r][2], x2, acc1[r])));
            }
            if (t > 0) {
                int rb = (t - 1) * 512 + quad * 128 + e * 8;
                bf16x8 bh = *(const bf16x8*)&shi[rb];
                bf16x8 bl = *(const bf16x8*)&slo[rb];
                acc0 = __builtin_amdgcn_mfma_f32_16x16x32_bf16(whh_h0, bh, acc0, 0, 0, 0);
                acc0 = __builtin_amdgcn_mfma_f32_16x16x32_bf16(whh_h0, bl, acc0, 0, 0, 0);
                acc0 = __builtin_amdgcn_mfma_f32_16x16x32_bf16(whh_l0, bh, acc0, 0, 0, 0);
                acc1 = __builtin_amdgcn_mfma_f32_16x16x32_bf16(whh_h1, bh, acc1, 0, 0, 0);
                acc1 = __builtin_amdgcn_mfma_f32_16x16x32_bf16(whh_h1, bl, acc1, 0, 0, 0);
                acc1 = __builtin_amdgcn_mfma_f32_16x16x32_bf16(whh_l1, bh, acc1, 0, 0, 0);
            }
            ACT_STORE(t);
        }
    }

    // ================= layers 1..4 (both projections via MFMA) ===========
    for (int l = 1; l < 5; ++l) {
        const float* Wi = WihR + (l - 1) * 4096;
        const float* Wh = Whh + l * 4096;
        LOAD_FRAG(Wi, orow_t0, wih_h0, wih_l0);
        LOAD_FRAG(Wi, orow_t1, wih_h1, wih_l1);
        LOAD_FRAG(Wh, orow_t0, whh_h0, whh_l0);
        LOAD_FRAG(Wh, orow_t1, whh_h1, whh_l1);
        LOAD_BIAS(l);
        c0 = 0.f; c1 = 0.f;

        for (int t = 0; t < T_STEPS; ++t) {
            f32x4 acc0 = {bias0[0], bias0[1], bias0[2], bias0[3]};
            f32x4 acc1 = {bias1[0], bias1[1], bias1[2], bias1[3]};
            // ih part: x = h_{l-1}(t), still in shi/slo[t] (pre-overwrite)
            {
                int rb = t * 512 + quad * 128 + e * 8;
                bf16x8 bh = *(const bf16x8*)&shi[rb];
                bf16x8 bl = *(const bf16x8*)&slo[rb];
                acc0 = __builtin_amdgcn_mfma_f32_16x16x32_bf16(wih_h0, bh, acc0, 0, 0, 0);
                acc0 = __builtin_amdgcn_mfma_f32_16x16x32_bf16(wih_h0, bl, acc0, 0, 0, 0);
                acc0 = __builtin_amdgcn_mfma_f32_16x16x32_bf16(wih_l0, bh, acc0, 0, 0, 0);
                acc1 = __builtin_amdgcn_mfma_f32_16x16x32_bf16(wih_h1, bh, acc1, 0, 0, 0);
                acc1 = __builtin_amdgcn_mfma_f32_16x16x32_bf16(wih_h1, bl, acc1, 0, 0, 0);
                acc1 = __builtin_amdgcn_mfma_f32_16x16x32_bf16(wih_l1, bh, acc1, 0, 0, 0);
            }
            if (t > 0) {
                int rb = (t - 1) * 512 + quad * 128 + e * 8;
                bf16x8 bh = *(const bf16x8*)&shi[rb];
                bf16x8 bl = *(const bf16x8*)&slo[rb];
                acc0 = __builtin_amdgcn_mfma_f32_16x16x32_bf16(whh_h0, bh, acc0, 0, 0, 0);
                acc0 = __builtin_amdgcn_mfma_f32_16x16x32_bf16(whh_h0, bl, acc0, 0, 0, 0);
                acc0 = __builtin_amdgcn_mfma_f32_16x16x32_bf16(whh_l0, bh, acc0, 0, 0, 0);
                acc1 = __builtin_amdgcn_mfma_f32_16x16x32_bf16(whh_h1, bh, acc1, 0, 0, 0);
                acc1 = __builtin_amdgcn_mfma_f32_16x16x32_bf16(whh_h1, bl, acc1, 0, 0, 0);
                acc1 = __builtin_amdgcn_mfma_f32_16x16x32_bf16(whh_l1, bh, acc1, 0, 0, 0);
            }
            ACT_STORE(t);
        }
    }

    // ---- epilogue: reconstruct fp32 h-seq, write to global for fc ----
    float* dst = hseq_out + ((size_t)sensor * B_TOTAL + bbase) * 640;
    for (int idx = tid; idx < 16 * 640; idx += 256) {
        int ee = idx / 640, r = idx - ee * 640;
        int t = r >> 5, u = r & 31;
        int sidx = t * 512 + (u >> 3) * 128 + ee * 8 + (u & 7);
        dst[idx] = (float)shi[sidx] + (float)slo[sidx];
    }
#undef LOAD_FRAG
#undef LOAD_BIAS
#undef ACT_STORE
}

// ---------------------------------------------------------------------------
// fc1_w [128][1280] -> W1T [1280][128] so fc reads are lane-coalesced
__global__ void transpose_w1(const float* __restrict__ w1, float* __restrict__ w1t) {
    int idx = blockIdx.x * blockDim.x + threadIdx.x;   // 1280*128
    int kk = idx >> 7, m = idx & 127;
    w1t[idx] = w1[m * 1280 + kk];
}

// ---------------------------------------------------------------------------
// Fused fc1 + ReLU + fc2. 256 thr = 32 m-quads x 8 b-quads; thread owns 4m x 4b.
__global__ __launch_bounds__(256, 2)
void fc_kernel(const float* __restrict__ hseqbuf, const float* __restrict__ w1t,
               const float* __restrict__ fc1_b, const float* __restrict__ fc2_w,
               const float* __restrict__ fc2_b, float* __restrict__ out) {
    const int tid = threadIdx.x;
    const int mq = tid & 31;          // m = 4*mq + mc
    const int bq = tid >> 5;          // 0..7
    const int b0 = blockIdx.x * 32 + bq * 4;

    float acc[4][4];
#pragma unroll
    for (int bi = 0; bi < 4; ++bi)
#pragma unroll
        for (int mc = 0; mc < 4; ++mc) acc[bi][mc] = 0.f;

    const float4* W1T4 = (const float4*)w1t;
    for (int half = 0; half < 2; ++half) {
        const float4* X4 = (const float4*)(hseqbuf + (size_t)half * B_TOTAL * 640);
        for (int c = 0; c < 80; ++c) {           // 8-kk chunks over 640
            float xs[4][8];
#pragma unroll
            for (int bi = 0; bi < 4; ++bi) {
                float4 u0 = X4[(b0 + bi) * 160 + c * 2];
                float4 u1 = X4[(b0 + bi) * 160 + c * 2 + 1];
                xs[bi][0] = u0.x; xs[bi][1] = u0.y; xs[bi][2] = u0.z; xs[bi][3] = u0.w;
                xs[bi][4] = u1.x; xs[bi][5] = u1.y; xs[bi][6] = u1.z; xs[bi][7] = u1.w;
            }
#pragma unroll
            for (int k = 0; k < 8; ++k) {
                float4 wv = W1T4[(half * 640 + c * 8 + k) * 32 + mq];
#pragma unroll
                for (int bi = 0; bi < 4; ++bi) {
                    float xv = xs[bi][k];
                    acc[bi][0] = fmaf(wv.x, xv, acc[bi][0]);
                    acc[bi][1] = fmaf(wv.y, xv, acc[bi][1]);
                    acc[bi][2] = fmaf(wv.z, xv, acc[bi][2]);
                    acc[bi][3] = fmaf(wv.w, xv, acc[bi][3]);
                }
            }
        }
    }

    // epilogue: bias + ReLU + fc2 partial + lane-reduce over mq
    float4 b1 = ((const float4*)fc1_b)[mq];
    float4 w2v[5];
#pragma unroll
    for (int n = 0; n < 5; ++n) w2v[n] = ((const float4*)fc2_w)[n * 32 + mq];

#pragma unroll
    for (int bi = 0; bi < 4; ++bi) {
        float v0 = fmaxf(acc[bi][0] + b1.x, 0.f);
        float v1 = fmaxf(acc[bi][1] + b1.y, 0.f);
        float v2 = fmaxf(acc[bi][2] + b1.z, 0.f);
        float v3 = fmaxf(acc[bi][3] + b1.w, 0.f);
        float p[5];
#pragma unroll
        for (int n = 0; n < 5; ++n) {
            p[n] = fmaf(v0, w2v[n].x, fmaf(v1, w2v[n].y, fmaf(v2, w2v[n].z, v3 * w2v[n].w)));
#pragma unroll
            for (int s = 16; s > 0; s >>= 1) p[n] += __shfl_down(p[n], s, 32);
        }
        if (mq == 0) {
#pragma unroll
            for (int n = 0; n < 5; ++n) out[(b0 + bi) * 5 + n] = p[n] + fc2_b[n];
        }
    }
}

// ---------------------------------------------------------------------------
extern "C" void kernel_launch(void* const* d_in, const int* in_sizes, int n_in,
                              void* d_out, int out_size, void* d_ws, size_t ws_size,
                              hipStream_t stream) {
    const float* accel  = (const float*)d_in[0];
    const float* gyro   = (const float*)d_in[1];
    const float* aWih0  = (const float*)d_in[2];
    const float* aWihR  = (const float*)d_in[3];
    const float* aWhh   = (const float*)d_in[4];
    const float* aBih   = (const float*)d_in[5];
    const float* aBhh   = (const float*)d_in[6];
    const float* gWih0  = (const float*)d_in[7];
    const float* gWihR  = (const float*)d_in[8];
    const float* gWhh   = (const float*)d_in[9];
    const float* gBih   = (const float*)d_in[10];
    const float* gBhh   = (const float*)d_in[11];
    const float* fc1_w  = (const float*)d_in[12];
    const float* fc1_b  = (const float*)d_in[13];
    const float* fc2_w  = (const float*)d_in[14];
    const float* fc2_b  = (const float*)d_in[15];
    float* out = (float*)d_out;

    float* ws      = (float*)d_ws;
    float* hseqbuf = ws;                              // 2*B*640 floats (84 MB)
    float* w1t     = ws + (size_t)2 * B_TOTAL * 640;  // 1280*128 floats

    hipLaunchKernelGGL(transpose_w1, dim3(640), dim3(256), 0, stream, fc1_w, w1t);

    hipLaunchKernelGGL(lstm5_mfma, dim3(B_TOTAL / 16, 2), dim3(256), 0, stream,
                       accel, gyro, aWih0, aWihR, aWhh, aBih, aBhh,
                       gWih0, gWihR, gWhh, gBih, gBhh, hseqbuf);

    hipLaunchKernelGGL(fc_kernel, dim3(B_TOTAL / 32), dim3(256), 0, stream,
                       hseqbuf, w1t, fc1_b, fc2_w, fc2_b, out);
}

// Round 4
// 448.931 us; speedup vs baseline: 2.4749x; 1.2456x over previous
//
#include <hip/hip_runtime.h>
#include <math.h>

#define B_TOTAL 16384
#define T_STEPS 20

typedef __attribute__((ext_vector_type(8))) __bf16 bf16x8;
typedef __attribute__((ext_vector_type(4))) float f32x4;

// ---------------------------------------------------------------------------
// Overflow-safe activations. v_rcp_f32 (1 ULP) instead of IEEE div sequence:
// without fast-math, "a/b" emits div_scale+rcp+3*fma+div_fmas+div_fixup
// (~10 instrs); rcpf is 1. rcp(inf)=0 gives exact saturation at extremes.
__device__ __forceinline__ float sigf(float x) {
    return __builtin_amdgcn_rcpf(1.0f + __expf(-x));
}
__device__ __forceinline__ float tanhf_fast(float x) {
    return fmaf(-2.0f, __builtin_amdgcn_rcpf(__expf(2.0f * x) + 1.0f), 1.0f);
}

// ---------------------------------------------------------------------------
// Fused 5-layer LSTM via bf16 MFMA with hi/lo compensation.
// Orientation: D[gate-rows][elems], gate-rows unit-major (row=u_local*4+gate)
// so each lane's 4 C-regs are the i,f,g,o of one unit -> acts in-register.
// Weights stationary in VGPRs (hi+lo A-frags). h-seq in LDS, hi/lo bf16,
// [t][chunk=u>>3][e][u&7] -> B-frag reads contiguous 1024B (conflict-free).
__global__ __launch_bounds__(256, 3)
void lstm5_mfma(const float* __restrict__ accel, const float* __restrict__ gyro,
                const float* __restrict__ aWih0, const float* __restrict__ aWihR,
                const float* __restrict__ aWhh,  const float* __restrict__ aBih,
                const float* __restrict__ aBhh,
                const float* __restrict__ gWih0, const float* __restrict__ gWihR,
                const float* __restrict__ gWhh,  const float* __restrict__ gBih,
                const float* __restrict__ gBhh,
                float* __restrict__ hseq_out /* [2][B][640] */) {
    const int tid  = threadIdx.x;
    const int w    = tid >> 6;        // wave 0..3
    const int lane = tid & 63;
    const int e    = lane & 15;       // elem (B-frag col / C col)
    const int quad = lane >> 4;       // 0..3
    const int sensor = blockIdx.y;
    const int bbase  = blockIdx.x * 16;

    const float* xin  = sensor ? gyro  : accel;
    const float* Wih0 = sensor ? gWih0 : aWih0;
    const float* WihR = sensor ? gWihR : aWihR;
    const float* Whh  = sensor ? gWhh  : aWhh;
    const float* Bih  = sensor ? gBih  : aBih;
    const float* Bhh  = sensor ? gBhh  : aBhh;

    __shared__ __align__(16) float  xs[960];          // [e][t][3]
    __shared__ __align__(16) __bf16 shi[20 * 512];    // [t][chunk][e][j]
    __shared__ __align__(16) __bf16 slo[20 * 512];

    // ---- stage layer-0 inputs (block's 16 elems are contiguous) ----
    {
        const float4* src = (const float4*)(xin + (size_t)bbase * 60);
        if (tid < 240) ((float4*)xs)[tid] = src[tid];
    }
    __syncthreads();

    // unit handled by (tile, quad):
    const int ug0 = (w * 2 + 0) * 4 + quad;   // tile 0 unit
    const int ug1 = (w * 2 + 1) * 4 + quad;   // tile 1 unit

    // A-frag loader: lane's row m = lane&15 -> (u_local=m>>2, gate=m&3);
    // orig W row = gate*32 + u_global; k-range = quad*8..+8.
    const int m_row   = lane & 15;
    const int ug_t0   = (w * 2 + 0) * 4 + (m_row >> 2);
    const int ug_t1   = (w * 2 + 1) * 4 + (m_row >> 2);
    const int orow_t0 = (m_row & 3) * 32 + ug_t0;
    const int orow_t1 = (m_row & 3) * 32 + ug_t1;

    bf16x8 wih_h0, wih_l0, wih_h1, wih_l1;
    bf16x8 whh_h0, whh_l0, whh_h1, whh_l1;
    f32x4  bias0v, bias1v;
    float  c0 = 0.f, c1 = 0.f;

#define LOAD_FRAG(Wsrc, orow, fh, fl)                         \
    {                                                         \
        const float* p_ = (Wsrc) + (orow) * 32 + quad * 8;    \
        _Pragma("unroll")                                     \
        for (int jj = 0; jj < 8; ++jj) {                      \
            float v_  = p_[jj];                               \
            __bf16 h_ = (__bf16)v_;                           \
            (fh)[jj]  = h_;                                   \
            (fl)[jj]  = (__bf16)(v_ - (float)h_);             \
        }                                                     \
    }

#define LOAD_BIAS(l)                                                        \
    {                                                                       \
        _Pragma("unroll")                                                   \
        for (int r = 0; r < 4; ++r) {                                       \
            bias0v[r] = Bih[(l) * 128 + r * 32 + ug0] + Bhh[(l) * 128 + r * 32 + ug0]; \
            bias1v[r] = Bih[(l) * 128 + r * 32 + ug1] + Bhh[(l) * 128 + r * 32 + ug1]; \
        }                                                                   \
    }

    // activation + h write (c0/c1 updated; h split hi/lo into LDS)
#define ACT_STORE(t)                                                        \
    {                                                                       \
        float i0 = sigf(acc0[0]), f0 = sigf(acc0[1]);                       \
        float g0 = tanhf_fast(acc0[2]), o0 = sigf(acc0[3]);                 \
        c0 = f0 * c0 + i0 * g0;                                             \
        float h0 = o0 * tanhf_fast(c0);                                     \
        float i1 = sigf(acc1[0]), f1 = sigf(acc1[1]);                       \
        float g1 = tanhf_fast(acc1[2]), o1 = sigf(acc1[3]);                 \
        c1 = f1 * c1 + i1 * g1;                                             \
        float h1 = o1 * tanhf_fast(c1);                                     \
        __syncthreads();  /* all waves done reading shi/slo[t] */           \
        int i0x = (t) * 512 + w * 128 + e * 8 + quad;                       \
        int i1x = i0x + 4;                                                  \
        __bf16 hh0 = (__bf16)h0;                                            \
        shi[i0x] = hh0; slo[i0x] = (__bf16)(h0 - (float)hh0);               \
        __bf16 hh1 = (__bf16)h1;                                            \
        shi[i1x] = hh1; slo[i1x] = (__bf16)(h1 - (float)hh1);               \
        __syncthreads();  /* writes visible before next step's reads */     \
    }

    // ================= layer 0 (ih is K=3, done in VALU) =================
    {
        LOAD_FRAG(Whh, orow_t0, whh_h0, whh_l0);
        LOAD_FRAG(Whh, orow_t1, whh_h1, whh_l1);
        LOAD_BIAS(0);
        float w0reg[2][4][3];
#pragma unroll
        for (int r = 0; r < 4; ++r)
#pragma unroll
            for (int k = 0; k < 3; ++k) {
                w0reg[0][r][k] = Wih0[(r * 32 + ug0) * 3 + k];
                w0reg[1][r][k] = Wih0[(r * 32 + ug1) * 3 + k];
            }
        c0 = 0.f; c1 = 0.f;

        for (int t = 0; t < T_STEPS; ++t) {
            f32x4 acc0 = bias0v;
            f32x4 acc1 = bias1v;
            float x0 = xs[e * 60 + t * 3 + 0];
            float x1 = xs[e * 60 + t * 3 + 1];
            float x2 = xs[e * 60 + t * 3 + 2];
#pragma unroll
            for (int r = 0; r < 4; ++r) {
                acc0[r] = fmaf(w0reg[0][r][0], x0,
                          fmaf(w0reg[0][r][1], x1,
                          fmaf(w0reg[0][r][2], x2, acc0[r])));
                acc1[r] = fmaf(w0reg[1][r][0], x0,
                          fmaf(w0reg[1][r][1], x1,
                          fmaf(w0reg[1][r][2], x2, acc1[r])));
            }
            if (t > 0) {
                int rb = (t - 1) * 512 + quad * 128 + e * 8;
                bf16x8 bh = *(const bf16x8*)&shi[rb];
                bf16x8 bl = *(const bf16x8*)&slo[rb];
                acc0 = __builtin_amdgcn_mfma_f32_16x16x32_bf16(whh_h0, bh, acc0, 0, 0, 0);
                acc0 = __builtin_amdgcn_mfma_f32_16x16x32_bf16(whh_h0, bl, acc0, 0, 0, 0);
                acc0 = __builtin_amdgcn_mfma_f32_16x16x32_bf16(whh_l0, bh, acc0, 0, 0, 0);
                acc1 = __builtin_amdgcn_mfma_f32_16x16x32_bf16(whh_h1, bh, acc1, 0, 0, 0);
                acc1 = __builtin_amdgcn_mfma_f32_16x16x32_bf16(whh_h1, bl, acc1, 0, 0, 0);
                acc1 = __builtin_amdgcn_mfma_f32_16x16x32_bf16(whh_l1, bh, acc1, 0, 0, 0);
            }
            ACT_STORE(t);
        }
    }

    // ================= layers 1..4 (both projections via MFMA) ===========
    for (int l = 1; l < 5; ++l) {
        const float* Wi = WihR + (l - 1) * 4096;
        const float* Wh = Whh + l * 4096;
        LOAD_FRAG(Wi, orow_t0, wih_h0, wih_l0);
        LOAD_FRAG(Wi, orow_t1, wih_h1, wih_l1);
        LOAD_FRAG(Wh, orow_t0, whh_h0, whh_l0);
        LOAD_FRAG(Wh, orow_t1, whh_h1, whh_l1);
        LOAD_BIAS(l);
        c0 = 0.f; c1 = 0.f;

        for (int t = 0; t < T_STEPS; ++t) {
            f32x4 acc0, acc1;
            // ih part: x = h_{l-1}(t), still in shi/slo[t] (pre-overwrite).
            // Bias rides in as the C operand of the first MFMA (D!=C legal).
            {
                int rb = t * 512 + quad * 128 + e * 8;
                bf16x8 bh = *(const bf16x8*)&shi[rb];
                bf16x8 bl = *(const bf16x8*)&slo[rb];
                acc0 = __builtin_amdgcn_mfma_f32_16x16x32_bf16(wih_h0, bh, bias0v, 0, 0, 0);
                acc0 = __builtin_amdgcn_mfma_f32_16x16x32_bf16(wih_h0, bl, acc0, 0, 0, 0);
                acc0 = __builtin_amdgcn_mfma_f32_16x16x32_bf16(wih_l0, bh, acc0, 0, 0, 0);
                acc1 = __builtin_amdgcn_mfma_f32_16x16x32_bf16(wih_h1, bh, bias1v, 0, 0, 0);
                acc1 = __builtin_amdgcn_mfma_f32_16x16x32_bf16(wih_h1, bl, acc1, 0, 0, 0);
                acc1 = __builtin_amdgcn_mfma_f32_16x16x32_bf16(wih_l1, bh, acc1, 0, 0, 0);
            }
            if (t > 0) {
                int rb = (t - 1) * 512 + quad * 128 + e * 8;
                bf16x8 bh = *(const bf16x8*)&shi[rb];
                bf16x8 bl = *(const bf16x8*)&slo[rb];
                acc0 = __builtin_amdgcn_mfma_f32_16x16x32_bf16(whh_h0, bh, acc0, 0, 0, 0);
                acc0 = __builtin_amdgcn_mfma_f32_16x16x32_bf16(whh_h0, bl, acc0, 0, 0, 0);
                acc0 = __builtin_amdgcn_mfma_f32_16x16x32_bf16(whh_l0, bh, acc0, 0, 0, 0);
                acc1 = __builtin_amdgcn_mfma_f32_16x16x32_bf16(whh_h1, bh, acc1, 0, 0, 0);
                acc1 = __builtin_amdgcn_mfma_f32_16x16x32_bf16(whh_h1, bl, acc1, 0, 0, 0);
                acc1 = __builtin_amdgcn_mfma_f32_16x16x32_bf16(whh_l1, bh, acc1, 0, 0, 0);
            }
            ACT_STORE(t);
        }
    }

    // ---- epilogue: reconstruct fp32 h-seq, write to global for fc ----
    float* dst = hseq_out + ((size_t)sensor * B_TOTAL + bbase) * 640;
    for (int idx = tid; idx < 16 * 640; idx += 256) {
        int ee = idx / 640, r = idx - ee * 640;
        int t = r >> 5, u = r & 31;
        int sidx = t * 512 + (u >> 3) * 128 + ee * 8 + (u & 7);
        dst[idx] = (float)shi[sidx] + (float)slo[sidx];
    }
#undef LOAD_FRAG
#undef LOAD_BIAS
#undef ACT_STORE
}

// ---------------------------------------------------------------------------
// fc1_w [128][1280] -> W1T [1280][128] so fc reads are lane-coalesced
__global__ void transpose_w1(const float* __restrict__ w1, float* __restrict__ w1t) {
    int idx = blockIdx.x * blockDim.x + threadIdx.x;   // 1280*128
    int kk = idx >> 7, m = idx & 127;
    w1t[idx] = w1[m * 1280 + kk];
}

// ---------------------------------------------------------------------------
// Fused fc1 + ReLU + fc2. 256 thr = 32 m-quads x 8 b-quads; thread owns 4m x 4b.
__global__ __launch_bounds__(256, 2)
void fc_kernel(const float* __restrict__ hseqbuf, const float* __restrict__ w1t,
               const float* __restrict__ fc1_b, const float* __restrict__ fc2_w,
               const float* __restrict__ fc2_b, float* __restrict__ out) {
    const int tid = threadIdx.x;
    const int mq = tid & 31;          // m = 4*mq + mc
    const int bq = tid >> 5;          // 0..7
    const int b0 = blockIdx.x * 32 + bq * 4;

    float acc[4][4];
#pragma unroll
    for (int bi = 0; bi < 4; ++bi)
#pragma unroll
        for (int mc = 0; mc < 4; ++mc) acc[bi][mc] = 0.f;

    const float4* W1T4 = (const float4*)w1t;
    for (int half = 0; half < 2; ++half) {
        const float4* X4 = (const float4*)(hseqbuf + (size_t)half * B_TOTAL * 640);
        for (int c = 0; c < 80; ++c) {           // 8-kk chunks over 640
            float xsv[4][8];
#pragma unroll
            for (int bi = 0; bi < 4; ++bi) {
                float4 u0 = X4[(b0 + bi) * 160 + c * 2];
                float4 u1 = X4[(b0 + bi) * 160 + c * 2 + 1];
                xsv[bi][0] = u0.x; xsv[bi][1] = u0.y; xsv[bi][2] = u0.z; xsv[bi][3] = u0.w;
                xsv[bi][4] = u1.x; xsv[bi][5] = u1.y; xsv[bi][6] = u1.z; xsv[bi][7] = u1.w;
            }
#pragma unroll
            for (int k = 0; k < 8; ++k) {
                float4 wv = W1T4[(half * 640 + c * 8 + k) * 32 + mq];
#pragma unroll
                for (int bi = 0; bi < 4; ++bi) {
                    float xv = xsv[bi][k];
                    acc[bi][0] = fmaf(wv.x, xv, acc[bi][0]);
                    acc[bi][1] = fmaf(wv.y, xv, acc[bi][1]);
                    acc[bi][2] = fmaf(wv.z, xv, acc[bi][2]);
                    acc[bi][3] = fmaf(wv.w, xv, acc[bi][3]);
                }
            }
        }
    }

    // epilogue: bias + ReLU + fc2 partial + lane-reduce over mq
    float4 b1 = ((const float4*)fc1_b)[mq];
    float4 w2v[5];
#pragma unroll
    for (int n = 0; n < 5; ++n) w2v[n] = ((const float4*)fc2_w)[n * 32 + mq];

#pragma unroll
    for (int bi = 0; bi < 4; ++bi) {
        float v0 = fmaxf(acc[bi][0] + b1.x, 0.f);
        float v1 = fmaxf(acc[bi][1] + b1.y, 0.f);
        float v2 = fmaxf(acc[bi][2] + b1.z, 0.f);
        float v3 = fmaxf(acc[bi][3] + b1.w, 0.f);
        float p[5];
#pragma unroll
        for (int n = 0; n < 5; ++n) {
            p[n] = fmaf(v0, w2v[n].x, fmaf(v1, w2v[n].y, fmaf(v2, w2v[n].z, v3 * w2v[n].w)));
#pragma unroll
            for (int s = 16; s > 0; s >>= 1) p[n] += __shfl_down(p[n], s, 32);
        }
        if (mq == 0) {
#pragma unroll
            for (int n = 0; n < 5; ++n) out[(b0 + bi) * 5 + n] = p[n] + fc2_b[n];
        }
    }
}

// ---------------------------------------------------------------------------
extern "C" void kernel_launch(void* const* d_in, const int* in_sizes, int n_in,
                              void* d_out, int out_size, void* d_ws, size_t ws_size,
                              hipStream_t stream) {
    const float* accel  = (const float*)d_in[0];
    const float* gyro   = (const float*)d_in[1];
    const float* aWih0  = (const float*)d_in[2];
    const float* aWihR  = (const float*)d_in[3];
    const float* aWhh   = (const float*)d_in[4];
    const float* aBih   = (const float*)d_in[5];
    const float* aBhh   = (const float*)d_in[6];
    const float* gWih0  = (const float*)d_in[7];
    const float* gWihR  = (const float*)d_in[8];
    const float* gWhh   = (const float*)d_in[9];
    const float* gBih   = (const float*)d_in[10];
    const float* gBhh   = (const float*)d_in[11];
    const float* fc1_w  = (const float*)d_in[12];
    const float* fc1_b  = (const float*)d_in[13];
    const float* fc2_w  = (const float*)d_in[14];
    const float* fc2_b  = (const float*)d_in[15];
    float* out = (float*)d_out;

    float* ws      = (float*)d_ws;
    float* hseqbuf = ws;                              // 2*B*640 floats (84 MB)
    float* w1t     = ws + (size_t)2 * B_TOTAL * 640;  // 1280*128 floats

    hipLaunchKernelGGL(transpose_w1, dim3(640), dim3(256), 0, stream, fc1_w, w1t);

    hipLaunchKernelGGL(lstm5_mfma, dim3(B_TOTAL / 16, 2), dim3(256), 0, stream,
                       accel, gyro, aWih0, aWihR, aWhh, aBih, aBhh,
                       gWih0, gWihR, gWhh, gBih, gBhh, hseqbuf);

    hipLaunchKernelGGL(fc_kernel, dim3(B_TOTAL / 32), dim3(256), 0, stream,
                       hseqbuf, w1t, fc1_b, fc2_w, fc2_b, out);
}

// Round 5
// 317.298 us; speedup vs baseline: 3.5016x; 1.4149x over previous
//
#include <hip/hip_runtime.h>
#include <math.h>

#define B_TOTAL 16384
#define T_STEPS 20
#define NGRP    1024            // B_TOTAL/16 batch groups per sensor

typedef __attribute__((ext_vector_type(8))) __bf16 bf16x8;
typedef __attribute__((ext_vector_type(4))) float f32x4;

// ---------------------------------------------------------------------------
__device__ __forceinline__ float sigf(float x) {
    return __builtin_amdgcn_rcpf(1.0f + __expf(-x));
}
__device__ __forceinline__ float tanhf_fast(float x) {
    return fmaf(-2.0f, __builtin_amdgcn_rcpf(__expf(2.0f * x) + 1.0f), 1.0f);
}

// Truncation-based Dekker split: hi = top-16-bits of x (exact residual),
// lo = top-16-bits of (x - hi). Cheaper than RNE casts (and/sub/shr only);
// dropped lo*lo MFMA term stays ~2^-16 relative.
__device__ __forceinline__ __bf16 bf16_bits(unsigned short s) {
    __bf16 r; __builtin_memcpy(&r, &s, 2); return r;
}
__device__ __forceinline__ void split_trunc(float x, __bf16& hi, __bf16& lo) {
    unsigned u = __float_as_uint(x);
    hi = bf16_bits((unsigned short)(u >> 16));
    float l = x - __uint_as_float(u & 0xFFFF0000u);
    lo = bf16_bits((unsigned short)(__float_as_uint(l) >> 16));
}

// ---------------------------------------------------------------------------
// Fused 5-layer LSTM via bf16 MFMA, hi/lo compensated.
// LDS = shi+slo = exactly 40 KiB -> 4 blocks/CU (16 waves/CU).
// Layout shi/slo[t][chunk=u>>3][e][u&7] == MFMA B-frag layout == the layout
// the fc GEMM consumes, so the epilogue is a raw float4 copy to global.
__global__ __launch_bounds__(256, 4)
void lstm5_mfma(const float* __restrict__ accel, const float* __restrict__ gyro,
                const float* __restrict__ aWih0, const float* __restrict__ aWihR,
                const float* __restrict__ aWhh,  const float* __restrict__ aBih,
                const float* __restrict__ aBhh,
                const float* __restrict__ gWih0, const float* __restrict__ gWihR,
                const float* __restrict__ gWhh,  const float* __restrict__ gBih,
                const float* __restrict__ gBhh,
                __bf16* __restrict__ Xhi, __bf16* __restrict__ Xlo) {
    const int tid  = threadIdx.x;
    const int w    = tid >> 6;        // wave 0..3
    const int lane = tid & 63;
    const int e    = lane & 15;       // elem (B-frag col / C col)
    const int quad = lane >> 4;       // 0..3
    const int sensor = blockIdx.y;
    const int bbase  = blockIdx.x * 16;

    const float* xin  = sensor ? gyro  : accel;
    const float* Wih0 = sensor ? gWih0 : aWih0;
    const float* WihR = sensor ? gWihR : aWihR;
    const float* Whh  = sensor ? gWhh  : aWhh;
    const float* Bih  = sensor ? gBih  : aBih;
    const float* Bhh  = sensor ? gBhh  : aBhh;

    __shared__ __align__(16) __bf16 shi[20 * 512];    // [t][chunk][e][j]
    __shared__ __align__(16) __bf16 slo[20 * 512];

    // unit handled by (tile, quad):
    const int ug0 = w * 8 + quad;        // tile 0 unit
    const int ug1 = w * 8 + 4 + quad;    // tile 1 unit

    // A-frag row mapping: m = lane&15 -> (u_local=m>>2, gate=m&3)
    const int m_row   = lane & 15;
    const int orow_t0 = (m_row & 3) * 32 + (w * 8 + (m_row >> 2));
    const int orow_t1 = (m_row & 3) * 32 + (w * 8 + 4 + (m_row >> 2));

    bf16x8 wih_h0, wih_l0, wih_h1, wih_l1;
    bf16x8 whh_h0, whh_l0, whh_h1, whh_l1;
    f32x4  bias0v, bias1v;
    float  c0 = 0.f, c1 = 0.f;

#define LOAD_FRAG(Wsrc, orow, fh, fl)                         \
    {                                                         \
        const float* p_ = (Wsrc) + (orow) * 32 + quad * 8;    \
        _Pragma("unroll")                                     \
        for (int jj = 0; jj < 8; ++jj) {                      \
            __bf16 h_, l_;                                    \
            split_trunc(p_[jj], h_, l_);                      \
            (fh)[jj] = h_;  (fl)[jj] = l_;                    \
        }                                                     \
    }

#define LOAD_BIAS(l)                                                        \
    {                                                                       \
        _Pragma("unroll")                                                   \
        for (int r = 0; r < 4; ++r) {                                       \
            bias0v[r] = Bih[(l) * 128 + r * 32 + ug0] + Bhh[(l) * 128 + r * 32 + ug0]; \
            bias1v[r] = Bih[(l) * 128 + r * 32 + ug1] + Bhh[(l) * 128 + r * 32 + ug1]; \
        }                                                                   \
    }

#define ACT_STORE(t)                                                        \
    {                                                                       \
        float i0 = sigf(acc0[0]), f0 = sigf(acc0[1]);                       \
        float g0 = tanhf_fast(acc0[2]), o0 = sigf(acc0[3]);                 \
        c0 = f0 * c0 + i0 * g0;                                             \
        float h0 = o0 * tanhf_fast(c0);                                     \
        float i1 = sigf(acc1[0]), f1 = sigf(acc1[1]);                       \
        float g1 = tanhf_fast(acc1[2]), o1 = sigf(acc1[3]);                 \
        c1 = f1 * c1 + i1 * g1;                                             \
        float h1 = o1 * tanhf_fast(c1);                                     \
        __syncthreads();  /* all waves done reading shi/slo[t] */           \
        int i0x = (t) * 512 + w * 128 + e * 8 + quad;                       \
        int i1x = i0x + 4;                                                  \
        __bf16 hh_, ll_;                                                    \
        split_trunc(h0, hh_, ll_);  shi[i0x] = hh_;  slo[i0x] = ll_;        \
        split_trunc(h1, hh_, ll_);  shi[i1x] = hh_;  slo[i1x] = ll_;        \
        __syncthreads();  /* writes visible before next step's reads */     \
    }

    // ================= layer 0 (ih is K=3, done in VALU) =================
    {
        LOAD_FRAG(Whh, orow_t0, whh_h0, whh_l0);
        LOAD_FRAG(Whh, orow_t1, whh_h1, whh_l1);
        LOAD_BIAS(0);
        float w0reg[2][4][3];
#pragma unroll
        for (int r = 0; r < 4; ++r)
#pragma unroll
            for (int k = 0; k < 3; ++k) {
                w0reg[0][r][k] = Wih0[(r * 32 + ug0) * 3 + k];
                w0reg[1][r][k] = Wih0[(r * 32 + ug1) * 3 + k];
            }
        const float* xrow = xin + (size_t)(bbase + e) * (T_STEPS * 3);

        for (int t = 0; t < T_STEPS; ++t) {
            // broadcast across quads; tiny, L1-resident after first pass
            float x0 = xrow[t * 3 + 0];
            float x1 = xrow[t * 3 + 1];
            float x2 = xrow[t * 3 + 2];
            f32x4 acc0 = bias0v;
            f32x4 acc1 = bias1v;
#pragma unroll
            for (int r = 0; r < 4; ++r) {
                acc0[r] = fmaf(w0reg[0][r][0], x0,
                          fmaf(w0reg[0][r][1], x1,
                          fmaf(w0reg[0][r][2], x2, acc0[r])));
                acc1[r] = fmaf(w0reg[1][r][0], x0,
                          fmaf(w0reg[1][r][1], x1,
                          fmaf(w0reg[1][r][2], x2, acc1[r])));
            }
            if (t > 0) {
                int rb = (t - 1) * 512 + quad * 128 + e * 8;
                bf16x8 bh = *(const bf16x8*)&shi[rb];
                bf16x8 bl = *(const bf16x8*)&slo[rb];
                acc0 = __builtin_amdgcn_mfma_f32_16x16x32_bf16(whh_h0, bh, acc0, 0, 0, 0);
                acc0 = __builtin_amdgcn_mfma_f32_16x16x32_bf16(whh_h0, bl, acc0, 0, 0, 0);
                acc0 = __builtin_amdgcn_mfma_f32_16x16x32_bf16(whh_l0, bh, acc0, 0, 0, 0);
                acc1 = __builtin_amdgcn_mfma_f32_16x16x32_bf16(whh_h1, bh, acc1, 0, 0, 0);
                acc1 = __builtin_amdgcn_mfma_f32_16x16x32_bf16(whh_h1, bl, acc1, 0, 0, 0);
                acc1 = __builtin_amdgcn_mfma_f32_16x16x32_bf16(whh_l1, bh, acc1, 0, 0, 0);
            }
            ACT_STORE(t);
        }
    }

    // ================= layers 1..4 (both projections via MFMA) ===========
    for (int l = 1; l < 5; ++l) {
        const float* Wi = WihR + (l - 1) * 4096;
        const float* Wh = Whh + l * 4096;
        LOAD_FRAG(Wi, orow_t0, wih_h0, wih_l0);
        LOAD_FRAG(Wi, orow_t1, wih_h1, wih_l1);
        LOAD_FRAG(Wh, orow_t0, whh_h0, whh_l0);
        LOAD_FRAG(Wh, orow_t1, whh_h1, whh_l1);
        LOAD_BIAS(l);
        c0 = 0.f; c1 = 0.f;

        for (int t = 0; t < T_STEPS; ++t) {
            f32x4 acc0, acc1;
            {   // ih: x = h_{l-1}(t); bias rides in as C of first MFMA
                int rb = t * 512 + quad * 128 + e * 8;
                bf16x8 bh = *(const bf16x8*)&shi[rb];
                bf16x8 bl = *(const bf16x8*)&slo[rb];
                acc0 = __builtin_amdgcn_mfma_f32_16x16x32_bf16(wih_h0, bh, bias0v, 0, 0, 0);
                acc0 = __builtin_amdgcn_mfma_f32_16x16x32_bf16(wih_h0, bl, acc0, 0, 0, 0);
                acc0 = __builtin_amdgcn_mfma_f32_16x16x32_bf16(wih_l0, bh, acc0, 0, 0, 0);
                acc1 = __builtin_amdgcn_mfma_f32_16x16x32_bf16(wih_h1, bh, bias1v, 0, 0, 0);
                acc1 = __builtin_amdgcn_mfma_f32_16x16x32_bf16(wih_h1, bl, acc1, 0, 0, 0);
                acc1 = __builtin_amdgcn_mfma_f32_16x16x32_bf16(wih_l1, bh, acc1, 0, 0, 0);
            }
            if (t > 0) {
                int rb = (t - 1) * 512 + quad * 128 + e * 8;
                bf16x8 bh = *(const bf16x8*)&shi[rb];
                bf16x8 bl = *(const bf16x8*)&slo[rb];
                acc0 = __builtin_amdgcn_mfma_f32_16x16x32_bf16(whh_h0, bh, acc0, 0, 0, 0);
                acc0 = __builtin_amdgcn_mfma_f32_16x16x32_bf16(whh_h0, bl, acc0, 0, 0, 0);
                acc0 = __builtin_amdgcn_mfma_f32_16x16x32_bf16(whh_l0, bh, acc0, 0, 0, 0);
                acc1 = __builtin_amdgcn_mfma_f32_16x16x32_bf16(whh_h1, bh, acc1, 0, 0, 0);
                acc1 = __builtin_amdgcn_mfma_f32_16x16x32_bf16(whh_h1, bl, acc1, 0, 0, 0);
                acc1 = __builtin_amdgcn_mfma_f32_16x16x32_bf16(whh_l1, bh, acc1, 0, 0, 0);
            }
            ACT_STORE(t);
        }
    }
    __syncthreads();

    // ---- epilogue: raw copy of frag-layout hi/lo to global for fc ----
    {
        size_t base = ((size_t)(sensor * NGRP + blockIdx.x)) * (20 * 512);
        float4* dh = (float4*)(Xhi + base);
        float4* dl = (float4*)(Xlo + base);
        const float4* sh = (const float4*)shi;
        const float4* sl = (const float4*)slo;
        for (int i = tid; i < 20 * 512 / 8; i += 256) { dh[i] = sh[i]; dl[i] = sl[i]; }
    }
#undef LOAD_FRAG
#undef LOAD_BIAS
#undef ACT_STORE
}

// ---------------------------------------------------------------------------
// fc1_w [128][1280] -> MFMA A-frag hi/lo arrays: [mt 0..7][ks 0..39][lane][8]
// lane row m = lane&15 -> fc1 row mt*16+m; k = (lane>>4)*8+j -> col ks*32+k.
__global__ void w1_prep(const float* __restrict__ w1,
                        __bf16* __restrict__ w1ah, __bf16* __restrict__ w1al) {
    int t = blockIdx.x * blockDim.x + threadIdx.x;     // 8*40*64 = 20480
    if (t >= 20480) return;
    int lane = t & 63;
    int ks   = (t >> 6) % 40;
    int mt   = t / (64 * 40);
    int row  = mt * 16 + (lane & 15);
    int col0 = ks * 32 + (lane >> 4) * 8;
    const float* src = w1 + row * 1280 + col0;
#pragma unroll
    for (int j = 0; j < 8; ++j) {
        __bf16 h_, l_;
        split_trunc(src[j], h_, l_);
        w1ah[t * 8 + j] = h_;
        w1al[t * 8 + j] = l_;
    }
}

// ---------------------------------------------------------------------------
// Fused fc1+ReLU+fc2 via hi/lo bf16 MFMA.
// Block 512 = 8 waves: wave = (mhalf 0..1) x (colgroup 0..3). Each wave:
// 4 m-tiles (64 fc1 rows) x 16 batch cols, K=1280 in 40 frag-steps.
// B-frags are direct bf16x8 loads from Xhi/Xlo (lstm's layout, no reshape).
__global__ __launch_bounds__(512, 2)
void fc_mfma(const __bf16* __restrict__ Xhi, const __bf16* __restrict__ Xlo,
             const __bf16* __restrict__ w1ah, const __bf16* __restrict__ w1al,
             const float* __restrict__ fc1_b, const float* __restrict__ fc2_w,
             const float* __restrict__ fc2_b, float* __restrict__ out) {
    const int tid   = threadIdx.x;
    const int wv    = tid >> 6;
    const int lane  = tid & 63;
    const int e     = lane & 15;
    const int quad  = lane >> 4;
    const int cg    = wv & 3;        // which 16-col group
    const int mhalf = wv >> 2;       // which 4 m-tiles

    __shared__ float sred[2][64][5];

    const int g = blockIdx.x * 4 + cg;    // global batch group (of 16 cols)

    f32x4 acc[4];
#pragma unroll
    for (int m = 0; m < 4; ++m) acc[m] = (f32x4){0.f, 0.f, 0.f, 0.f};

    for (int sensor = 0; sensor < 2; ++sensor) {
        const __bf16* bh_base = Xhi + ((size_t)(sensor * NGRP + g)) * (20 * 512) + lane * 8;
        const __bf16* bl_base = Xlo + ((size_t)(sensor * NGRP + g)) * (20 * 512) + lane * 8;
        for (int t = 0; t < T_STEPS; ++t) {
            int ks = sensor * 20 + t;
            bf16x8 bh = *(const bf16x8*)(bh_base + t * 512);
            bf16x8 bl = *(const bf16x8*)(bl_base + t * 512);
#pragma unroll
            for (int m = 0; m < 4; ++m) {
                int mt = mhalf * 4 + m;
                const __bf16* ap = w1ah + ((size_t)(mt * 40 + ks) * 64 + lane) * 8;
                const __bf16* al = w1al + ((size_t)(mt * 40 + ks) * 64 + lane) * 8;
                bf16x8 ah = *(const bf16x8*)ap;
                bf16x8 av = *(const bf16x8*)al;
                acc[m] = __builtin_amdgcn_mfma_f32_16x16x32_bf16(ah, bh, acc[m], 0, 0, 0);
                acc[m] = __builtin_amdgcn_mfma_f32_16x16x32_bf16(ah, bl, acc[m], 0, 0, 0);
                acc[m] = __builtin_amdgcn_mfma_f32_16x16x32_bf16(av, bh, acc[m], 0, 0, 0);
            }
        }
    }

    // epilogue: bias + ReLU + partial fc2 over this wave's 64 rows
    float p[5] = {0.f, 0.f, 0.f, 0.f, 0.f};
#pragma unroll
    for (int m = 0; m < 4; ++m) {
        int mt = mhalf * 4 + m;
#pragma unroll
        for (int r = 0; r < 4; ++r) {
            int row = mt * 16 + quad * 4 + r;       // C row = quad*4 + reg
            float v = fmaxf(acc[m][r] + fc1_b[row], 0.f);
#pragma unroll
            for (int n = 0; n < 5; ++n) p[n] = fmaf(v, fc2_w[n * 128 + row], p[n]);
        }
    }
    // butterfly over quad bits (lanes e, e+16, e+32, e+48 hold disjoint rows)
#pragma unroll
    for (int n = 0; n < 5; ++n) {
        p[n] += __shfl_xor(p[n], 16, 64);
        p[n] += __shfl_xor(p[n], 32, 64);
    }
    if (quad == 0) {
#pragma unroll
        for (int n = 0; n < 5; ++n) sred[mhalf][cg * 16 + e][n] = p[n];
    }
    __syncthreads();
    if (tid < 320) {
        int col = tid / 5, n = tid - col * 5;
        out[(size_t)(blockIdx.x * 64 + col) * 5 + n] =
            sred[0][col][n] + sred[1][col][n] + fc2_b[n];
    }
}

// ---------------------------------------------------------------------------
extern "C" void kernel_launch(void* const* d_in, const int* in_sizes, int n_in,
                              void* d_out, int out_size, void* d_ws, size_t ws_size,
                              hipStream_t stream) {
    const float* accel  = (const float*)d_in[0];
    const float* gyro   = (const float*)d_in[1];
    const float* aWih0  = (const float*)d_in[2];
    const float* aWihR  = (const float*)d_in[3];
    const float* aWhh   = (const float*)d_in[4];
    const float* aBih   = (const float*)d_in[5];
    const float* aBhh   = (const float*)d_in[6];
    const float* gWih0  = (const float*)d_in[7];
    const float* gWihR  = (const float*)d_in[8];
    const float* gWhh   = (const float*)d_in[9];
    const float* gBih   = (const float*)d_in[10];
    const float* gBhh   = (const float*)d_in[11];
    const float* fc1_w  = (const float*)d_in[12];
    const float* fc1_b  = (const float*)d_in[13];
    const float* fc2_w  = (const float*)d_in[14];
    const float* fc2_b  = (const float*)d_in[15];
    float* out = (float*)d_out;

    const size_t XN = (size_t)2 * NGRP * 20 * 512;    // 20,971,520 bf16 each
    __bf16* Xhi  = (__bf16*)d_ws;
    __bf16* Xlo  = Xhi + XN;
    __bf16* W1ah = Xlo + XN;                          // 163,840 bf16 each
    __bf16* W1al = W1ah + 163840;

    hipLaunchKernelGGL(w1_prep, dim3(80), dim3(256), 0, stream, fc1_w, W1ah, W1al);

    hipLaunchKernelGGL(lstm5_mfma, dim3(NGRP, 2), dim3(256), 0, stream,
                       accel, gyro, aWih0, aWihR, aWhh, aBih, aBhh,
                       gWih0, gWihR, gWhh, gBih, gBhh, Xhi, Xlo);

    hipLaunchKernelGGL(fc_mfma, dim3(B_TOTAL / 64), dim3(512), 0, stream,
                       Xhi, Xlo, W1ah, W1al, fc1_b, fc2_w, fc2_b, out);
}

// Round 6
// 291.745 us; speedup vs baseline: 3.8083x; 1.0876x over previous
//
#include <hip/hip_runtime.h>
#include <math.h>

#define B_TOTAL 16384
#define T_STEPS 20
#define NGRP    1024            // B_TOTAL/16 batch groups per sensor

typedef __attribute__((ext_vector_type(8))) __bf16 bf16x8;
typedef __attribute__((ext_vector_type(4))) float f32x4;

// ---------------------------------------------------------------------------
__device__ __forceinline__ float sigf(float x) {
    return __builtin_amdgcn_rcpf(1.0f + __expf(-x));
}
__device__ __forceinline__ float tanhf_fast(float x) {
    return fmaf(-2.0f, __builtin_amdgcn_rcpf(__expf(2.0f * x) + 1.0f), 1.0f);
}

// Truncation-based Dekker split: hi = top-16-bits of x (exact residual),
// lo = top-16-bits of (x - hi).
__device__ __forceinline__ __bf16 bf16_bits(unsigned short s) {
    __bf16 r; __builtin_memcpy(&r, &s, 2); return r;
}
__device__ __forceinline__ void split_trunc(float x, __bf16& hi, __bf16& lo) {
    unsigned u = __float_as_uint(x);
    hi = bf16_bits((unsigned short)(u >> 16));
    float l = x - __uint_as_float(u & 0xFFFF0000u);
    lo = bf16_bits((unsigned short)(__float_as_uint(l) >> 16));
}

// ---------------------------------------------------------------------------
// Fused 5-layer LSTM via bf16 MFMA, hi/lo compensated. (unchanged from R5)
__global__ __launch_bounds__(256, 4)
void lstm5_mfma(const float* __restrict__ accel, const float* __restrict__ gyro,
                const float* __restrict__ aWih0, const float* __restrict__ aWihR,
                const float* __restrict__ aWhh,  const float* __restrict__ aBih,
                const float* __restrict__ aBhh,
                const float* __restrict__ gWih0, const float* __restrict__ gWihR,
                const float* __restrict__ gWhh,  const float* __restrict__ gBih,
                const float* __restrict__ gBhh,
                __bf16* __restrict__ Xhi, __bf16* __restrict__ Xlo) {
    const int tid  = threadIdx.x;
    const int w    = tid >> 6;        // wave 0..3
    const int lane = tid & 63;
    const int e    = lane & 15;       // elem (B-frag col / C col)
    const int quad = lane >> 4;       // 0..3
    const int sensor = blockIdx.y;
    const int bbase  = blockIdx.x * 16;

    const float* xin  = sensor ? gyro  : accel;
    const float* Wih0 = sensor ? gWih0 : aWih0;
    const float* WihR = sensor ? gWihR : aWihR;
    const float* Whh  = sensor ? gWhh  : aWhh;
    const float* Bih  = sensor ? gBih  : aBih;
    const float* Bhh  = sensor ? gBhh  : aBhh;

    __shared__ __align__(16) __bf16 shi[20 * 512];    // [t][chunk][e][j]
    __shared__ __align__(16) __bf16 slo[20 * 512];

    const int ug0 = w * 8 + quad;        // tile 0 unit
    const int ug1 = w * 8 + 4 + quad;    // tile 1 unit

    const int m_row   = lane & 15;
    const int orow_t0 = (m_row & 3) * 32 + (w * 8 + (m_row >> 2));
    const int orow_t1 = (m_row & 3) * 32 + (w * 8 + 4 + (m_row >> 2));

    bf16x8 wih_h0, wih_l0, wih_h1, wih_l1;
    bf16x8 whh_h0, whh_l0, whh_h1, whh_l1;
    f32x4  bias0v, bias1v;
    float  c0 = 0.f, c1 = 0.f;

#define LOAD_FRAG(Wsrc, orow, fh, fl)                         \
    {                                                         \
        const float* p_ = (Wsrc) + (orow) * 32 + quad * 8;    \
        _Pragma("unroll")                                     \
        for (int jj = 0; jj < 8; ++jj) {                      \
            __bf16 h_, l_;                                    \
            split_trunc(p_[jj], h_, l_);                      \
            (fh)[jj] = h_;  (fl)[jj] = l_;                    \
        }                                                     \
    }

#define LOAD_BIAS(l)                                                        \
    {                                                                       \
        _Pragma("unroll")                                                   \
        for (int r = 0; r < 4; ++r) {                                       \
            bias0v[r] = Bih[(l) * 128 + r * 32 + ug0] + Bhh[(l) * 128 + r * 32 + ug0]; \
            bias1v[r] = Bih[(l) * 128 + r * 32 + ug1] + Bhh[(l) * 128 + r * 32 + ug1]; \
        }                                                                   \
    }

#define ACT_STORE(t)                                                        \
    {                                                                       \
        float i0 = sigf(acc0[0]), f0 = sigf(acc0[1]);                       \
        float g0 = tanhf_fast(acc0[2]), o0 = sigf(acc0[3]);                 \
        c0 = f0 * c0 + i0 * g0;                                             \
        float h0 = o0 * tanhf_fast(c0);                                     \
        float i1 = sigf(acc1[0]), f1 = sigf(acc1[1]);                       \
        float g1 = tanhf_fast(acc1[2]), o1 = sigf(acc1[3]);                 \
        c1 = f1 * c1 + i1 * g1;                                             \
        float h1 = o1 * tanhf_fast(c1);                                     \
        __syncthreads();  /* all waves done reading shi/slo[t] */           \
        int i0x = (t) * 512 + w * 128 + e * 8 + quad;                       \
        int i1x = i0x + 4;                                                  \
        __bf16 hh_, ll_;                                                    \
        split_trunc(h0, hh_, ll_);  shi[i0x] = hh_;  slo[i0x] = ll_;        \
        split_trunc(h1, hh_, ll_);  shi[i1x] = hh_;  slo[i1x] = ll_;        \
        __syncthreads();  /* writes visible before next step's reads */     \
    }

    // ================= layer 0 (ih is K=3, done in VALU) =================
    {
        LOAD_FRAG(Whh, orow_t0, whh_h0, whh_l0);
        LOAD_FRAG(Whh, orow_t1, whh_h1, whh_l1);
        LOAD_BIAS(0);
        float w0reg[2][4][3];
#pragma unroll
        for (int r = 0; r < 4; ++r)
#pragma unroll
            for (int k = 0; k < 3; ++k) {
                w0reg[0][r][k] = Wih0[(r * 32 + ug0) * 3 + k];
                w0reg[1][r][k] = Wih0[(r * 32 + ug1) * 3 + k];
            }
        const float* xrow = xin + (size_t)(bbase + e) * (T_STEPS * 3);

        for (int t = 0; t < T_STEPS; ++t) {
            float x0 = xrow[t * 3 + 0];
            float x1 = xrow[t * 3 + 1];
            float x2 = xrow[t * 3 + 2];
            f32x4 acc0 = bias0v;
            f32x4 acc1 = bias1v;
#pragma unroll
            for (int r = 0; r < 4; ++r) {
                acc0[r] = fmaf(w0reg[0][r][0], x0,
                          fmaf(w0reg[0][r][1], x1,
                          fmaf(w0reg[0][r][2], x2, acc0[r])));
                acc1[r] = fmaf(w0reg[1][r][0], x0,
                          fmaf(w0reg[1][r][1], x1,
                          fmaf(w0reg[1][r][2], x2, acc1[r])));
            }
            if (t > 0) {
                int rb = (t - 1) * 512 + quad * 128 + e * 8;
                bf16x8 bh = *(const bf16x8*)&shi[rb];
                bf16x8 bl = *(const bf16x8*)&slo[rb];
                acc0 = __builtin_amdgcn_mfma_f32_16x16x32_bf16(whh_h0, bh, acc0, 0, 0, 0);
                acc0 = __builtin_amdgcn_mfma_f32_16x16x32_bf16(whh_h0, bl, acc0, 0, 0, 0);
                acc0 = __builtin_amdgcn_mfma_f32_16x16x32_bf16(whh_l0, bh, acc0, 0, 0, 0);
                acc1 = __builtin_amdgcn_mfma_f32_16x16x32_bf16(whh_h1, bh, acc1, 0, 0, 0);
                acc1 = __builtin_amdgcn_mfma_f32_16x16x32_bf16(whh_h1, bl, acc1, 0, 0, 0);
                acc1 = __builtin_amdgcn_mfma_f32_16x16x32_bf16(whh_l1, bh, acc1, 0, 0, 0);
            }
            ACT_STORE(t);
        }
    }

    // ================= layers 1..4 (both projections via MFMA) ===========
    for (int l = 1; l < 5; ++l) {
        const float* Wi = WihR + (l - 1) * 4096;
        const float* Wh = Whh + l * 4096;
        LOAD_FRAG(Wi, orow_t0, wih_h0, wih_l0);
        LOAD_FRAG(Wi, orow_t1, wih_h1, wih_l1);
        LOAD_FRAG(Wh, orow_t0, whh_h0, whh_l0);
        LOAD_FRAG(Wh, orow_t1, whh_h1, whh_l1);
        LOAD_BIAS(l);
        c0 = 0.f; c1 = 0.f;

        for (int t = 0; t < T_STEPS; ++t) {
            f32x4 acc0, acc1;
            {   // ih: x = h_{l-1}(t); bias rides in as C of first MFMA
                int rb = t * 512 + quad * 128 + e * 8;
                bf16x8 bh = *(const bf16x8*)&shi[rb];
                bf16x8 bl = *(const bf16x8*)&slo[rb];
                acc0 = __builtin_amdgcn_mfma_f32_16x16x32_bf16(wih_h0, bh, bias0v, 0, 0, 0);
                acc0 = __builtin_amdgcn_mfma_f32_16x16x32_bf16(wih_h0, bl, acc0, 0, 0, 0);
                acc0 = __builtin_amdgcn_mfma_f32_16x16x32_bf16(wih_l0, bh, acc0, 0, 0, 0);
                acc1 = __builtin_amdgcn_mfma_f32_16x16x32_bf16(wih_h1, bh, bias1v, 0, 0, 0);
                acc1 = __builtin_amdgcn_mfma_f32_16x16x32_bf16(wih_h1, bl, acc1, 0, 0, 0);
                acc1 = __builtin_amdgcn_mfma_f32_16x16x32_bf16(wih_l1, bh, acc1, 0, 0, 0);
            }
            if (t > 0) {
                int rb = (t - 1) * 512 + quad * 128 + e * 8;
                bf16x8 bh = *(const bf16x8*)&shi[rb];
                bf16x8 bl = *(const bf16x8*)&slo[rb];
                acc0 = __builtin_amdgcn_mfma_f32_16x16x32_bf16(whh_h0, bh, acc0, 0, 0, 0);
                acc0 = __builtin_amdgcn_mfma_f32_16x16x32_bf16(whh_h0, bl, acc0, 0, 0, 0);
                acc0 = __builtin_amdgcn_mfma_f32_16x16x32_bf16(whh_l0, bh, acc0, 0, 0, 0);
                acc1 = __builtin_amdgcn_mfma_f32_16x16x32_bf16(whh_h1, bh, acc1, 0, 0, 0);
                acc1 = __builtin_amdgcn_mfma_f32_16x16x32_bf16(whh_h1, bl, acc1, 0, 0, 0);
                acc1 = __builtin_amdgcn_mfma_f32_16x16x32_bf16(whh_l1, bh, acc1, 0, 0, 0);
            }
            ACT_STORE(t);
        }
    }
    __syncthreads();

    // ---- epilogue: raw copy of frag-layout hi/lo to global for fc ----
    {
        size_t base = ((size_t)(sensor * NGRP + blockIdx.x)) * (20 * 512);
        float4* dh = (float4*)(Xhi + base);
        float4* dl = (float4*)(Xlo + base);
        const float4* sh = (const float4*)shi;
        const float4* sl = (const float4*)slo;
        for (int i = tid; i < 20 * 512 / 8; i += 256) { dh[i] = sh[i]; dl[i] = sl[i]; }
    }
#undef LOAD_FRAG
#undef LOAD_BIAS
#undef ACT_STORE
}

// ---------------------------------------------------------------------------
// fc1_w [128][1280] -> MFMA A-frag hi/lo arrays: [mt 0..7][ks 0..39][lane][8]
__global__ void w1_prep(const float* __restrict__ w1,
                        __bf16* __restrict__ w1ah, __bf16* __restrict__ w1al) {
    int t = blockIdx.x * blockDim.x + threadIdx.x;     // 8*40*64 = 20480
    if (t >= 20480) return;
    int lane = t & 63;
    int ks   = (t >> 6) % 40;
    int mt   = t / (64 * 40);
    int row  = mt * 16 + (lane & 15);
    int col0 = ks * 32 + (lane >> 4) * 8;
    const float* src = w1 + row * 1280 + col0;
#pragma unroll
    for (int j = 0; j < 8; ++j) {
        __bf16 h_, l_;
        split_trunc(src[j], h_, l_);
        w1ah[t * 8 + j] = h_;
        w1al[t * 8 + j] = l_;
    }
}

// ---------------------------------------------------------------------------
// Fused fc1+ReLU+fc2, K-split: block = 256 thr / 4 waves owns 16 batch cols;
// wave wv handles ks = wv*10 .. wv*10+9 (of 40) for ALL 8 m-tiles; C-partials
// reduced through LDS. W1 frags are read ONCE per block (655 KB -> 671 MB
// total L2 traffic vs 2.7 GB in the per-wave-replicated version).
__global__ __launch_bounds__(256, 4)
void fc_mfma(const __bf16* __restrict__ Xhi, const __bf16* __restrict__ Xlo,
             const __bf16* __restrict__ w1ah, const __bf16* __restrict__ w1al,
             const float* __restrict__ fc1_b, const float* __restrict__ fc2_w,
             const float* __restrict__ fc2_b, float* __restrict__ out) {
    const int tid  = threadIdx.x;
    const int wv   = tid >> 6;       // ks-quarter
    const int lane = tid & 63;
    const int e    = lane & 15;
    const int quad = lane >> 4;
    const int g    = blockIdx.x;     // batch group (16 cols)

    __shared__ __align__(16) f32x4 sacc[4][8][64];   // 32 KB C-partials
    __shared__ float sred[4][16][5];

    f32x4 acc[8];
#pragma unroll
    for (int m = 0; m < 8; ++m) acc[m] = (f32x4){0.f, 0.f, 0.f, 0.f};

    for (int kk = 0; kk < 10; ++kk) {
        int ks = wv * 10 + kk;                 // 0..39
        int sensor = ks / 20, t = ks % 20;     // col = sensor*640 + t*32 + u
        size_t bb = ((size_t)(sensor * NGRP + g)) * (20 * 512) + t * 512 + lane * 8;
        bf16x8 bh = *(const bf16x8*)(Xhi + bb);
        bf16x8 bl = *(const bf16x8*)(Xlo + bb);
#pragma unroll
        for (int m = 0; m < 8; ++m) {
            const __bf16* ap = w1ah + ((size_t)((m * 40 + ks) * 64 + lane)) * 8;
            const __bf16* al = w1al + ((size_t)((m * 40 + ks) * 64 + lane)) * 8;
            bf16x8 ah = *(const bf16x8*)ap;
            bf16x8 av = *(const bf16x8*)al;
            acc[m] = __builtin_amdgcn_mfma_f32_16x16x32_bf16(ah, bh, acc[m], 0, 0, 0);
            acc[m] = __builtin_amdgcn_mfma_f32_16x16x32_bf16(ah, bl, acc[m], 0, 0, 0);
            acc[m] = __builtin_amdgcn_mfma_f32_16x16x32_bf16(av, bh, acc[m], 0, 0, 0);
        }
    }
#pragma unroll
    for (int m = 0; m < 8; ++m) sacc[wv][m][lane] = acc[m];
    __syncthreads();

    // phase 2: wave wv reduces m-tiles {2wv, 2wv+1}: sum K-partials, bias,
    // ReLU, fc2 partial over its rows; butterfly over quad bits.
    float p[5] = {0.f, 0.f, 0.f, 0.f, 0.f};
#pragma unroll
    for (int mm = 0; mm < 2; ++mm) {
        int mt = wv * 2 + mm;
        f32x4 z = sacc[0][mt][lane];
#pragma unroll
        for (int k = 1; k < 4; ++k) {
            f32x4 zz = sacc[k][mt][lane];
#pragma unroll
            for (int r = 0; r < 4; ++r) z[r] += zz[r];
        }
#pragma unroll
        for (int r = 0; r < 4; ++r) {
            int row = mt * 16 + quad * 4 + r;      // C row = quad*4 + reg
            float v = fmaxf(z[r] + fc1_b[row], 0.f);
#pragma unroll
            for (int n = 0; n < 5; ++n) p[n] = fmaf(v, fc2_w[n * 128 + row], p[n]);
        }
    }
#pragma unroll
    for (int n = 0; n < 5; ++n) {
        p[n] += __shfl_xor(p[n], 16, 64);
        p[n] += __shfl_xor(p[n], 32, 64);
    }
    if (quad == 0) {
#pragma unroll
        for (int n = 0; n < 5; ++n) sred[wv][e][n] = p[n];
    }
    __syncthreads();
    if (tid < 80) {
        int col = tid / 5, n = tid - col * 5;
        out[(size_t)(g * 16 + col) * 5 + n] =
            sred[0][col][n] + sred[1][col][n] + sred[2][col][n] + sred[3][col][n] + fc2_b[n];
    }
}

// ---------------------------------------------------------------------------
extern "C" void kernel_launch(void* const* d_in, const int* in_sizes, int n_in,
                              void* d_out, int out_size, void* d_ws, size_t ws_size,
                              hipStream_t stream) {
    const float* accel  = (const float*)d_in[0];
    const float* gyro   = (const float*)d_in[1];
    const float* aWih0  = (const float*)d_in[2];
    const float* aWihR  = (const float*)d_in[3];
    const float* aWhh   = (const float*)d_in[4];
    const float* aBih   = (const float*)d_in[5];
    const float* aBhh   = (const float*)d_in[6];
    const float* gWih0  = (const float*)d_in[7];
    const float* gWihR  = (const float*)d_in[8];
    const float* gWhh   = (const float*)d_in[9];
    const float* gBih   = (const float*)d_in[10];
    const float* gBhh   = (const float*)d_in[11];
    const float* fc1_w  = (const float*)d_in[12];
    const float* fc1_b  = (const float*)d_in[13];
    const float* fc2_w  = (const float*)d_in[14];
    const float* fc2_b  = (const float*)d_in[15];
    float* out = (float*)d_out;

    const size_t XN = (size_t)2 * NGRP * 20 * 512;    // 20,971,520 bf16 each
    __bf16* Xhi  = (__bf16*)d_ws;
    __bf16* Xlo  = Xhi + XN;
    __bf16* W1ah = Xlo + XN;                          // 163,840 bf16 each
    __bf16* W1al = W1ah + 163840;

    hipLaunchKernelGGL(w1_prep, dim3(80), dim3(256), 0, stream, fc1_w, W1ah, W1al);

    hipLaunchKernelGGL(lstm5_mfma, dim3(NGRP, 2), dim3(256), 0, stream,
                       accel, gyro, aWih0, aWihR, aWhh, aBih, aBhh,
                       gWih0, gWihR, gWhh, gBih, gBhh, Xhi, Xlo);

    hipLaunchKernelGGL(fc_mfma, dim3(NGRP), dim3(256), 0, stream,
                       Xhi, Xlo, W1ah, W1al, fc1_b, fc2_w, fc2_b, out);
}